// Round 12
// baseline (784.062 us; speedup 1.0000x reference)
//
#include <hip/hip_runtime.h>

typedef unsigned char u8;
typedef unsigned short u16;
typedef unsigned int u32;
typedef __attribute__((ext_vector_type(8))) short short8;
typedef __attribute__((ext_vector_type(8))) u16 u16x8;
typedef __attribute__((ext_vector_type(4))) float f32x4;
typedef __attribute__((ext_vector_type(4))) int i32x4;
typedef __attribute__((ext_vector_type(8))) int i32x8;

#define N_NODES 5000
#define NP 5120
#define BTOT 96
#define J_DIM 6144
#define TT 24
#define KNEG 20

__device__ __forceinline__ float b2f(u16 u){ union{u32 i; float f;} x; x.i = ((u32)u)<<16; return x.f; }
__device__ __forceinline__ u16 f2b(float f){ union{float fl; u32 i;} x; x.fl = f; u32 r = (x.i + 0x7fffu + ((x.i>>16)&1u))>>16; return (u16)r; }
__device__ __forceinline__ u8 f2e4(float f){ return (u8)(__builtin_amdgcn_cvt_pk_fp8_f32(f, 0.f, 0, false) & 0xff); }

#define GPERM(r) ((((r)>>1)&3) | (((r)&1)<<2))
#define GLOAD16(g, l) __builtin_amdgcn_global_load_lds((const __attribute__((address_space(1))) void*)(g), (__attribute__((address_space(3))) void*)(l), 16, 0, 0)

// ---------------- tiny precompute (+normalized t<4 vectors) ----------------
__global__ void k_prep(const float* __restrict__ Ws, const float* __restrict__ bs,
                       const float* __restrict__ W1, const float* __restrict__ b1,
                       const float* __restrict__ W2, const float* __restrict__ b2,
                       float* __restrict__ consts, u16* __restrict__ w2t)
{
  int d = threadIdx.x; // 64 threads
  float u0=0.f,u1=0.f,u2=0.f,bb=0.f;
  for (int c=0;c<64;c++){
    float w = Ws[c];
    float a = W1[c*64+d], b_ = W1[(64+c)*64+d], cw = W1[(128+c)*64+d];
    u0 += w*a; u1 += w*b_; u2 += w*cw;
    bb += bs[c]*(a+b_+cw);
  }
  bb += b1[d];
  consts[d]=u0; consts[64+d]=u1; consts[128+d]=u2; consts[192+d]=bb;
  __shared__ float rb[64];
  rb[d] = fmaxf(bb, 0.f);
  __syncthreads();
  float cA=0.f,cB=0.f,cC=0.f;
  for (int c=0;c<64;c++){
    float r = rb[c];
    cA += r*W2[c*64+d]; cB += r*W2[(64+c)*64+d]; cC += r*W2[(128+c)*64+d];
  }
  consts[256+d]=cA; consts[320+d]=cB; consts[384+d]=cC;
  for (int c=0;c<192;c++) w2t[d*192 + c] = f2b(W2[c*64 + d]);
  __syncthreads();
  // 4 normalized t<4 vectors: vi = r1 + 2*r2
  float b2v = b2[d];
  for (int vi=0; vi<4; vi++){
    float vv = cA + ((vi&1) ? cB : 0.f) + ((vi&2) ? cC : 0.f) + b2v;
    rb[d] = vv*vv;
    __syncthreads();
    for (int o=32;o;o>>=1){ if (d<o) rb[d]+=rb[d+o]; __syncthreads(); }
    float nrm = sqrtf(rb[0]);
    consts[448 + vi*64 + d] = vv / fmaxf(nrm, 1e-8f);
    __syncthreads();
  }
}

// ------- adj -> fp8 (A and A^T), exact f32 degrees via shuffle (no LDS atomics) -------
__global__ __launch_bounds__(256) void k_convT(const float* __restrict__ adj,
    u8* __restrict__ abf, u8* __restrict__ atbf,
    float* __restrict__ degr, float* __restrict__ degc)
{
  __shared__ u8 tN[64][80];
  __shared__ u8 tT[64][80];
  __shared__ float rsum[64];
  __shared__ float cpart[16][64];
  const int tid = threadIdx.x;
  const int bx = blockIdx.x, by = blockIdx.y;
  const int c4 = (tid & 15) * 4;
  const int g  = tid >> 4;
  const int gk = bx*64 + c4;
  float ca0=0.f, ca1=0.f, ca2=0.f, ca3=0.f;
  #pragma unroll
  for (int p=0;p<4;p++){
    int r = p*16 + g;
    int gm = by*64 + r;
    float v0=0.f,v1=0.f,v2=0.f,v3=0.f;
    if (gm < N_NODES && gk + 3 < N_NODES){
      const float4 v = *(const float4*)(adj + (size_t)gm*N_NODES + gk);
      v0=v.x; v1=v.y; v2=v.z; v3=v.w;
    }
    u8 p0=f2e4(v0), p1=f2e4(v1), p2=f2e4(v2), p3=f2e4(v3);
    *(u32*)&tN[r][c4] = (u32)p0 | ((u32)p1<<8) | ((u32)p2<<16) | ((u32)p3<<24);
    tT[c4+0][r]=p0; tT[c4+1][r]=p1; tT[c4+2][r]=p2; tT[c4+3][r]=p3;
    float ls = v0+v1+v2+v3;
    ls += __shfl_xor(ls,1); ls += __shfl_xor(ls,2);
    ls += __shfl_xor(ls,4); ls += __shfl_xor(ls,8);
    if ((tid & 15) == 0) rsum[r] = ls;
    ca0+=v0; ca1+=v1; ca2+=v2; ca3+=v3;
  }
  cpart[g][c4+0]=ca0; cpart[g][c4+1]=ca1; cpart[g][c4+2]=ca2; cpart[g][c4+3]=ca3;
  __syncthreads();
  if (tid < 64){
    int gm = by*64 + tid;
    if (gm < N_NODES && rsum[tid] != 0.f) atomicAdd(&degr[gm], rsum[tid]);
    float cs = 0.f;
    #pragma unroll
    for (int gg=0;gg<16;gg++) cs += cpart[gg][tid];
    int gc = bx*64 + tid;
    if (gc < N_NODES && cs != 0.f) atomicAdd(&degc[gc], cs);
  }
  const int j = tid >> 2, c16 = (tid & 3) * 16;
  *(i32x4*)(abf  + (size_t)(by*64+j)*NP + bx*64 + c16) = *(const i32x4*)(&tN[j][c16]);
  *(i32x4*)(atbf + (size_t)(bx*64+j)*NP + by*64 + c16) = *(const i32x4*)(&tT[j][c16]);
}

// ---------------- x -> fp8 [128][5120] padded ----------------
__global__ void k_xbf(const float* __restrict__ x, u8* __restrict__ xbf){
  int i4 = (blockIdx.x*256 + threadIdx.x)*4;
  int j = i4 / NP, n = i4 - j*NP;
  u32 w = 0;
  if (j < BTOT){
    #pragma unroll
    for (int e=0;e<4;e++){
      float v = (n+e < N_NODES) ? x[(size_t)j*N_NODES + n + e] : 0.f;
      w |= ((u32)f2e4(v)) << (8*e);
    }
  }
  *(u32*)(xbf + i4) = w;
}

// ======= shared fp8 MFMA tile machinery (verified geometry) =======
__device__ __forceinline__ i32x8 frag8(const u8* lds, int row, int kb2){
  int g = GPERM(row & 7);
  int ba = row*128 + ((kb2 ^ g)<<4);
  union { i32x8 v; i32x4 h[2]; } f;
  f.h[0] = *(const i32x4*)(lds + ba);
  f.h[1] = *(const i32x4*)(lds + (ba^16));
  return f.v;
}

// ------- ysl[ks][5120][128] = A(fp8) @ xbf(fp8)^T, counted-vmcnt pipeline -------
__global__ __launch_bounds__(256) void k_sgemm8(const u8* __restrict__ abf,
    const u8* __restrict__ atbf, const u8* __restrict__ B,
    float* __restrict__ y1sl, float* __restrict__ y2sl)
{
  __shared__ __align__(16) u8 lA[2][16384];
  __shared__ __align__(16) u8 lB[2][16384];
  const u8* A = blockIdx.z ? atbf : abf;
  float* ysl = blockIdx.z ? y2sl : y1sl;
  const int tid = threadIdx.x, lane = tid & 63, wv = tid >> 6;
  const int wm = (wv >> 1) * 64, wj = (wv & 1) * 64;
  const int m0 = blockIdx.x * 128;
  const int kbase = blockIdx.y * 640;
  f32x4 acc[4][4] = {};
  const int q = tid >> 3;
  const int sc = ((tid & 7) ^ GPERM(q & 7)) << 4;
  const u8* gA = A + (size_t)(m0 + q)*NP + kbase + sc;
  const u8* gB = B + (size_t)q*NP + kbase + sc;

  #define SSTAGE8(k0, bufA, bufB) do { \
    _Pragma("unroll") \
    for (int s=0;s<4;s++){ \
      GLOAD16(gA + (size_t)(s*32)*NP + (k0), (char*)(bufA) + s*4096 + wv*1024); \
      GLOAD16(gB + (size_t)(s*32)*NP + (k0), (char*)(bufB) + s*4096 + wv*1024); \
    } \
  } while(0)

  SSTAGE8(0,   lA[0], lB[0]);
  SSTAGE8(128, lA[1], lB[1]);
  asm volatile("s_waitcnt vmcnt(8)" ::: "memory");
  __builtin_amdgcn_s_barrier();
  __builtin_amdgcn_sched_barrier(0);

  for (int t = 0; t < 5; t++) {
    const int cur = t & 1;
    const u8* bA = lA[cur];
    const u8* bB = lB[cur];
    i32x8 af[4], bfv[4];
    const int kb2 = (lane >> 4) * 2;
    #pragma unroll
    for (int i=0;i<4;i++){
      af[i]  = frag8(bA, wm + i*16 + (lane&15), kb2);
      bfv[i] = frag8(bB, wj + i*16 + (lane&15), kb2);
    }
    __builtin_amdgcn_s_setprio(1);
    #pragma unroll
    for (int i=0;i<4;i++)
      #pragma unroll
      for (int j=0;j<4;j++)
        acc[i][j] = __builtin_amdgcn_mfma_scale_f32_16x16x128_f8f6f4(
            af[i], bfv[j], acc[i][j], 0, 0, 0, 0x7f7f7f7f, 0, 0x7f7f7f7f);
    __builtin_amdgcn_s_setprio(0);
    __builtin_amdgcn_s_barrier();
    __builtin_amdgcn_sched_barrier(0);
    if (t + 2 < 5) {
      SSTAGE8((t+2)*128, lA[cur], lB[cur]);
      asm volatile("s_waitcnt vmcnt(8)" ::: "memory");
    } else {
      asm volatile("s_waitcnt vmcnt(0)" ::: "memory");
    }
    __builtin_amdgcn_s_barrier();
    __builtin_amdgcn_sched_barrier(0);
  }
  #undef SSTAGE8

  float* yb = ysl + (size_t)blockIdx.y * NP * 128;
  #pragma unroll
  for (int i=0;i<4;i++)
    #pragma unroll
    for (int r=0;r<4;r++){
      int row = m0 + wm + i*16 + (lane>>4)*4 + r;
      #pragma unroll
      for (int j=0;j<4;j++){
        int col = wj + j*16 + (lane&15);
        yb[(size_t)row*128 + col] = acc[i][j][r];
      }
    }
}

// ------- reduce 8 K-slices, fold 1/deg, transpose to y[bt][n] -------
__global__ __launch_bounds__(256) void k_yred(const float* __restrict__ y1sl,
    const float* __restrict__ y2sl, const float* __restrict__ degr,
    const float* __restrict__ degc, float* __restrict__ y1r, float* __restrict__ y2r)
{
  __shared__ float tb[128][66];
  const int n0 = blockIdx.x*64;
  const int bt = threadIdx.x & 127, nh = threadIdx.x >> 7;
  const int nl = threadIdx.x & 63, bh = threadIdx.x >> 6;
  #pragma unroll 4
  for (int k=0;k<32;k++){
    int n = nh*32 + k;
    float s = 0.f;
    #pragma unroll
    for (int sl=0; sl<8; sl++) s += y1sl[((size_t)sl*NP + n0+n)*128 + bt];
    tb[bt][n] = s;
  }
  __syncthreads();
  {
    float dv = degr[n0+nl];
    float iv = (dv > 0.f) ? 1.f/dv : 0.f;
    #pragma unroll 4
    for (int b=0;b<32;b++){
      int btw = bh*32 + b;
      y1r[(size_t)btw*NP + n0 + nl] = iv * tb[btw][nl];
    }
  }
  __syncthreads();
  #pragma unroll 4
  for (int k=0;k<32;k++){
    int n = nh*32 + k;
    float s = 0.f;
    #pragma unroll
    for (int sl=0; sl<8; sl++) s += y2sl[((size_t)sl*NP + n0+n)*128 + bt];
    tb[bt][n] = s;
  }
  __syncthreads();
  {
    float dv = degc[n0+nl];
    float iv = (dv > 0.f) ? 1.f/dv : 0.f;
    #pragma unroll 4
    for (int b=0;b<32;b++){
      int btw = bh*32 + b;
      y2r[(size_t)btw*NP + n0 + nl] = iv * tb[btw][nl];
    }
  }
}

// ------- layer-1: h1t(fp8) [j][n] via LDS transpose + h1n(bf16) [n][j] -------
// reindexed: 4 consecutive lanes cover one 128B h1n row (coalesced stores)
__global__ __launch_bounds__(256) void k_h1(const float* __restrict__ x,
    const float* __restrict__ y1r, const float* __restrict__ y2r,
    const float* __restrict__ consts, u8* __restrict__ h1t, u16* __restrict__ h1n)
{
  __shared__ u8 trT[64][80];
  const int tid = threadIdx.x;
  const int n = tid >> 2, d0 = (tid & 3) * 16;
  const int n0 = blockIdx.x * 64;
  const int bt = blockIdx.y;
  const int gn = n0 + n;
  const bool valid = gn < N_NODES;
  float xv  = valid ? x[(size_t)bt*N_NODES + gn] : 0.f;
  float y1s = y1r[(size_t)bt*NP + gn];
  float y2s = y2r[(size_t)bt*NP + gn];
  float hv[16];
  #pragma unroll
  for (int e=0;e<16;e++){
    int d = d0 + e;
    float v = 0.f;
    if (valid)
      v = fmaxf(xv*consts[d] + y1s*consts[64+d] + y2s*consts[128+d] + consts[192+d], 0.f);
    hv[e] = v;
    trT[d][n] = f2e4(v);
  }
  u16x8 p0, p1;
  #pragma unroll
  for (int e=0;e<8;e++){ p0[e]=f2b(hv[e]); p1[e]=f2b(hv[8+e]); }
  u16* dst = h1n + (size_t)gn*J_DIM + bt*64 + d0;
  *(u16x8*)dst = p0;
  *(u16x8*)(dst+8) = p1;
  __syncthreads();
  const int d = tid >> 2, c16 = (tid & 3) * 16;
  *(i32x4*)(h1t + (size_t)(bt*64+d)*NP + n0 + c16) = *(const i32x4*)(&trT[d][c16]);
}

// ------- big GEMM (z-merged P/Q), 128x128, counted-vmcnt, XCD-chunked swizzle -------
__global__ __launch_bounds__(256) void k_gemm8(
    const u8* __restrict__ abf, const u8* __restrict__ atbf,
    const u8* __restrict__ Bt, u16* __restrict__ Pb, u16* __restrict__ Qb,
    const float* __restrict__ degr, const float* __restrict__ degc)
{
  __shared__ __align__(16) u8 lA[2][16384];
  __shared__ __align__(16) u8 lB[2][16384];
  // XCD-chunked swizzle: 3840 blocks = 8 XCDs x 480; each XCD gets 12
  // consecutive y (B-panels reused 40x from its L2) sweeping all x.
  const int lin = blockIdx.x + 40*blockIdx.y + 1920*blockIdx.z;
  const int swz = (lin & 7)*480 + (lin >> 3);
  const int bz = swz / 1920;
  const int rem = swz - bz*1920;
  const int byi = rem / 40;
  const int bxi = rem - byi*40;
  const u8* A = bz ? atbf : abf;
  u16* C = bz ? Qb : Pb;
  const float* dg = bz ? degc : degr;
  const int tid = threadIdx.x, lane = tid & 63, wv = tid >> 6;
  const int wm = (wv >> 1) * 64, wj = (wv & 1) * 64;
  const int m0 = bxi * 128;
  const int j0 = byi * 128;
  f32x4 acc[4][4] = {};
  const int q = tid >> 3;
  const int sc = ((tid & 7) ^ GPERM(q & 7)) << 4;
  const u8* gA = A + (size_t)(m0 + q)*NP + sc;
  const u8* gB = Bt + (size_t)(j0 + q)*NP + sc;

  #define STAGE8(k0, bufA, bufB) do { \
    _Pragma("unroll") \
    for (int s=0;s<4;s++){ \
      GLOAD16(gA + (size_t)(s*32)*NP + (k0), (char*)(bufA) + s*4096 + wv*1024); \
      GLOAD16(gB + (size_t)(s*32)*NP + (k0), (char*)(bufB) + s*4096 + wv*1024); \
    } \
  } while(0)

  STAGE8(0,   lA[0], lB[0]);
  STAGE8(128, lA[1], lB[1]);
  asm volatile("s_waitcnt vmcnt(8)" ::: "memory");
  __builtin_amdgcn_s_barrier();
  __builtin_amdgcn_sched_barrier(0);

  const int NT = NP/128;  // 40
  for (int t = 0; t < NT; t++) {
    const int cur = t & 1;
    const u8* bA = lA[cur];
    const u8* bB = lB[cur];
    i32x8 af[4], bfv[4];
    const int kb2 = (lane >> 4) * 2;
    #pragma unroll
    for (int i=0;i<4;i++){
      af[i]  = frag8(bA, wm + i*16 + (lane&15), kb2);
      bfv[i] = frag8(bB, wj + i*16 + (lane&15), kb2);
    }
    __builtin_amdgcn_s_setprio(1);
    #pragma unroll
    for (int i=0;i<4;i++)
      #pragma unroll
      for (int j=0;j<4;j++)
        acc[i][j] = __builtin_amdgcn_mfma_scale_f32_16x16x128_f8f6f4(
            af[i], bfv[j], acc[i][j], 0, 0, 0, 0x7f7f7f7f, 0, 0x7f7f7f7f);
    __builtin_amdgcn_s_setprio(0);
    __builtin_amdgcn_s_barrier();
    __builtin_amdgcn_sched_barrier(0);
    if (t + 2 < NT) {
      STAGE8((t+2)*128, lA[cur], lB[cur]);
      asm volatile("s_waitcnt vmcnt(8)" ::: "memory");
    } else {
      asm volatile("s_waitcnt vmcnt(0)" ::: "memory");
    }
    __builtin_amdgcn_s_barrier();
    __builtin_amdgcn_sched_barrier(0);
  }
  #undef STAGE8

  #pragma unroll
  for (int i=0;i<4;i++)
    #pragma unroll
    for (int r=0;r<4;r++){
      int row = m0 + wm + i*16 + (lane>>4)*4 + r;
      float dv = dg[row];
      float scl = (dv > 0.f) ? 1.f/dv : 0.f;
      #pragma unroll
      for (int j=0;j<4;j++){
        int col = j0 + wj + j*16 + (lane&15);
        C[(size_t)row*J_DIM + col] = f2b(acc[i][j][r] * scl);
      }
    }
}

// ------- fused layer-2 + head + row-normalize (bf16 P/Q, R9-proven) -------
__global__ __launch_bounds__(256) void k_comb(const u16* __restrict__ h1n,
  const u16* __restrict__ P, const u16* __restrict__ Q,
  const u16* __restrict__ w2t, const float* __restrict__ b2,
  const float* __restrict__ Wf1, const float* __restrict__ bf1,
  const float* __restrict__ Wf2, const float* __restrict__ bf2,
  u16* __restrict__ horin, float* __restrict__ yout)
{
  __shared__ float w1L[64*33];
  __shared__ float hT[64][65];
  __shared__ float b1L[32], w2Ls[32];
  const int tid = threadIdx.x;
  for (int i = tid; i < 2048; i += 256) w1L[(i>>5)*33 + (i&31)] = Wf1[i];
  if (tid < 32){ b1L[tid] = bf1[tid]; w2Ls[tid] = Wf2[tid]; }
  const int lane = tid & 63;
  const int wv = tid >> 6;
  const int n0 = blockIdx.x * 64 + wv * 16;
  const int bt = blockIdx.y;
  const int rl = lane & 15, kh = lane >> 4;

  f32x4 acc[4] = {};
  const size_t rowoff = (size_t)(n0 + rl) * J_DIM + bt*64;
  const u16* bases[3] = { h1n + rowoff, P + rowoff, Q + rowoff };
  #pragma unroll
  for (int s=0;s<3;s++){
    const u16* base = bases[s];
    #pragma unroll
    for (int kk=0;kk<2;kk++){
      short8 af = *(const short8*)(base + kk*32 + kh*8);
      #pragma unroll
      for (int j=0;j<4;j++){
        short8 bf = *(const short8*)(w2t + (j*16+rl)*192 + s*64 + kk*32 + kh*8);
        acc[j] = __builtin_amdgcn_mfma_f32_16x16x32_bf16(af, bf, acc[j], 0,0,0);
      }
    }
  }
  float hvv[4][4];
  #pragma unroll
  for (int j=0;j<4;j++){
    float bias = b2[j*16 + rl];
    #pragma unroll
    for (int r=0;r<4;r++) hvv[j][r] = acc[j][r] + bias;
  }
  float inv[4];
  #pragma unroll
  for (int r=0;r<4;r++){
    float s = hvv[0][r]*hvv[0][r] + hvv[1][r]*hvv[1][r]
            + hvv[2][r]*hvv[2][r] + hvv[3][r]*hvv[3][r];
    s += __shfl_xor(s,1); s += __shfl_xor(s,2);
    s += __shfl_xor(s,4); s += __shfl_xor(s,8);
    inv[r] = 1.f / fmaxf(sqrtf(s), 1e-8f);
  }
  #pragma unroll
  for (int j=0;j<4;j++){
    int d = j*16 + rl;
    #pragma unroll
    for (int r=0;r<4;r++){
      int nn = n0 + kh*4 + r;
      hT[wv*16 + kh*4 + r][d] = hvv[j][r];
      if (nn < N_NODES)
        horin[((size_t)bt*N_NODES + nn)*64 + d] = f2b(hvv[j][r] * inv[r]);
    }
  }
  __syncthreads();
  const int qd = tid & 3, node = tid >> 2;
  float h[16];
  #pragma unroll
  for (int e=0;e<16;e++) h[e] = hT[node][qd*16 + e];
  float yacc = 0.f;
  #pragma unroll
  for (int jj=0; jj<32; jj++){
    float s = 0.f;
    #pragma unroll
    for (int dl=0; dl<16; dl++) s += h[dl]*w1L[(qd*16+dl)*33 + jj];
    s += __shfl_xor(s, 1);
    s += __shfl_xor(s, 2);
    s += b1L[jj];
    yacc += fmaxf(s, 0.f)*w2Ls[jj];
  }
  int gn = blockIdx.x*64 + node;
  if (qd == 0 && gn < N_NODES)
    yout[(size_t)bt*N_NODES + gn] = yacc + bf2[0];
}

// ---------------- InfoNCE loss (pre-normalized rows, unrolled ILP) ----------------
__global__ __launch_bounds__(256) void k_loss(const u16* __restrict__ horin,
  const int* __restrict__ missing, const int* __restrict__ posi, const int* __restrict__ negi,
  const float* __restrict__ degr, const float* __restrict__ degc,
  const float* __restrict__ consts, float* __restrict__ out)
{
  const int lane = threadIdx.x & 63;
  const int wv = threadIdx.x >> 6;
  const int wg = blockIdx.x*4 + wv;   // 0..24575
  const int m = wg & 255;
  const int bt = wg >> 8;
  const bool early = (bt % TT) < 4;

  int na = missing[m];
  float va = b2f(horin[((size_t)bt*N_NODES + na)*64 + lane]);

  float lk[KNEG+1];
  #pragma unroll
  for (int k=0;k<=KNEG;k++){
    int node = (k==0) ? posi[m] : negi[m*KNEG + (k-1)];
    float v;
    if (!early) v = b2f(horin[((size_t)bt*N_NODES + node)*64 + lane]);
    else {
      int vi = (degr[node] > 0.f ? 1 : 0) + (degc[node] > 0.f ? 2 : 0);
      v = consts[448 + vi*64 + lane];
    }
    float dp = va*v;
    #pragma unroll
    for (int o=32;o;o>>=1) dp += __shfl_xor(dp, o);
    lk[k] = dp * 2.f;   // /TEMP, TEMP=0.5
  }
  float mx = lk[0];
  #pragma unroll
  for (int k=1;k<=KNEG;k++) mx = fmaxf(mx, lk[k]);
  float se = 0.f;
  #pragma unroll
  for (int k=0;k<=KNEG;k++) se += expf(lk[k]-mx);
  float term = logf(se) + mx - lk[0];
  __shared__ float red[4];
  if (lane == 0) red[wv] = term;
  __syncthreads();
  if (threadIdx.x == 0)
    atomicAdd(out + 480000, (red[0]+red[1]+red[2]+red[3]) * (1.f/24576.f));
}

extern "C" void kernel_launch(void* const* d_in, const int* in_sizes, int n_in,
                              void* d_out, int out_size, void* d_ws, size_t ws_size,
                              hipStream_t stream)
{
  const float* x   = (const float*)d_in[0];
  const float* adj = (const float*)d_in[1];
  const float* Ws  = (const float*)d_in[2];
  const float* bs  = (const float*)d_in[3];
  const float* W1  = (const float*)d_in[4];
  const float* b1  = (const float*)d_in[5];
  const float* W2  = (const float*)d_in[6];
  const float* b2  = (const float*)d_in[7];
  const float* Wf1 = (const float*)d_in[8];
  const float* bf1 = (const float*)d_in[9];
  const float* Wf2 = (const float*)d_in[10];
  const float* bf2 = (const float*)d_in[11];
  const int* missing = (const int*)d_in[12];
  const int* posi    = (const int*)d_in[13];
  const int* negi    = (const int*)d_in[14];
  float* out = (float*)d_out;

  char* w = (char*)d_ws;
  u8*  abf   = (u8*) (w + 0);             // 26,214,400
  u8*  atbf  = (u8*) (w + 26214400);      // 26,214,400
  u8*  h1t   = (u8*) (w + 52428800);      // 31,457,280
  u16* h1n   = (u16*)(w + 83886080);      // 62,914,560 (bf16 self term)
  u16* Pb    = (u16*)(w + 146800640);     // 62,914,560
  u16* Qb    = (u16*)(w + 209715200);     // 62,914,560
  u8*  xbf   = (u8*) (w + 272629760);     // 655,360
  float* degr = (float*)(w + 273285120);  // 20480
  float* degc = (float*)(w + 273305600);  // 20480
  float* consts = (float*)(w + 273326080);// 4096 (704 floats)
  u16* w2t   = (u16*)(w + 273330176);     // 24576
  // aliases (temporally disjoint):
  u16*   horin = (u16*)(w + 0);           // 61,440,000 over abf/atbf/h1t (dead post-gemms)
  float* y1sl  = (float*)(w + 146800640); // 8 x NP x 128 f32 = 20,971,520 (in Pb)
  float* y2sl  = (float*)(w + 167772160); // 20,971,520 (in Pb)
  float* y1r   = (float*)(w + 209715200); // 128 x NP f32 = 2,621,440 (in Qb, dead pre-gemm-Q)
  float* y2r   = (float*)(w + 212336640); // 2,621,440

  hipMemsetAsync(degr, 0, 40960, stream);         // degr+degc (contiguous)
  hipMemsetAsync(out + 480000, 0, 4, stream);     // loss accumulator

  k_prep<<<1, 64, 0, stream>>>(Ws, bs, W1, b1, W2, b2, consts, w2t);
  k_convT<<<dim3(80,80), 256, 0, stream>>>(adj, abf, atbf, degr, degc);
  k_xbf<<<640, 256, 0, stream>>>(x, xbf);
  k_sgemm8<<<dim3(40,8,2), 256, 0, stream>>>(abf, atbf, xbf, y1sl, y2sl);
  k_yred<<<80, 256, 0, stream>>>(y1sl, y2sl, degr, degc, y1r, y2r);
  k_h1<<<dim3(80,96), 256, 0, stream>>>(x, y1r, y2r, consts, h1t, h1n);
  k_gemm8<<<dim3(40,48,2), 256, 0, stream>>>(abf, atbf, h1t, Pb, Qb, degr, degc);
  k_comb<<<dim3(80,96), 256, 0, stream>>>(h1n, Pb, Qb, w2t, b2, Wf1, bf1, Wf2, bf2, horin, out);
  k_loss<<<6144, 256, 0, stream>>>(horin, missing, posi, negi, degr, degc, consts, out);
}

// Round 14
// 665.019 us; speedup vs baseline: 1.1790x; 1.1790x over previous
//
#include <hip/hip_runtime.h>

typedef unsigned char u8;
typedef unsigned short u16;
typedef unsigned int u32;
typedef __attribute__((ext_vector_type(8))) short short8;
typedef __attribute__((ext_vector_type(8))) u16 u16x8;
typedef __attribute__((ext_vector_type(4))) float f32x4;
typedef __attribute__((ext_vector_type(4))) int i32x4;
typedef __attribute__((ext_vector_type(8))) int i32x8;

#define N_NODES 5000
#define NP 5120
#define BTOT 96
#define J_DIM 6144
#define TT 24
#define KNEG 20

__device__ __forceinline__ float b2f(u16 u){ union{u32 i; float f;} x; x.i = ((u32)u)<<16; return x.f; }
__device__ __forceinline__ u16 f2b(float f){ union{float fl; u32 i;} x; x.fl = f; u32 r = (x.i + 0x7fffu + ((x.i>>16)&1u))>>16; return (u16)r; }
__device__ __forceinline__ u8 f2e4(float f){ return (u8)(__builtin_amdgcn_cvt_pk_fp8_f32(f, 0.f, 0, false) & 0xff); }

#define GPERM(r) ((((r)>>1)&3) | (((r)&1)<<2))
#define GLOAD16(g, l) __builtin_amdgcn_global_load_lds((const __attribute__((address_space(1))) void*)(g), (__attribute__((address_space(3))) void*)(l), 16, 0, 0)
#define CFENCE() asm volatile("" ::: "memory")

// ---------------- tiny precompute (+normalized t<4 vectors) ----------------
__global__ void k_prep(const float* __restrict__ Ws, const float* __restrict__ bs,
                       const float* __restrict__ W1, const float* __restrict__ b1,
                       const float* __restrict__ W2, const float* __restrict__ b2,
                       float* __restrict__ consts, u16* __restrict__ w2t)
{
  int d = threadIdx.x; // 64 threads
  float u0=0.f,u1=0.f,u2=0.f,bb=0.f;
  for (int c=0;c<64;c++){
    float w = Ws[c];
    float a = W1[c*64+d], b_ = W1[(64+c)*64+d], cw = W1[(128+c)*64+d];
    u0 += w*a; u1 += w*b_; u2 += w*cw;
    bb += bs[c]*(a+b_+cw);
  }
  bb += b1[d];
  consts[d]=u0; consts[64+d]=u1; consts[128+d]=u2; consts[192+d]=bb;
  __shared__ float rb[64];
  rb[d] = fmaxf(bb, 0.f);
  __syncthreads();
  float cA=0.f,cB=0.f,cC=0.f;
  for (int c=0;c<64;c++){
    float r = rb[c];
    cA += r*W2[c*64+d]; cB += r*W2[(64+c)*64+d]; cC += r*W2[(128+c)*64+d];
  }
  consts[256+d]=cA; consts[320+d]=cB; consts[384+d]=cC;
  for (int c=0;c<192;c++) w2t[d*192 + c] = f2b(W2[c*64 + d]);
  __syncthreads();
  // 4 normalized t<4 vectors: vi = r1 + 2*r2
  float b2v = b2[d];
  for (int vi=0; vi<4; vi++){
    float vv = cA + ((vi&1) ? cB : 0.f) + ((vi&2) ? cC : 0.f) + b2v;
    rb[d] = vv*vv;
    __syncthreads();
    for (int o=32;o;o>>=1){ if (d<o) rb[d]+=rb[d+o]; __syncthreads(); }
    float nrm = sqrtf(rb[0]);
    consts[448 + vi*64 + d] = vv / fmaxf(nrm, 1e-8f);
    __syncthreads();
  }
}

// ------- adj -> fp8 (A and A^T), exact f32 degrees via shuffle (no LDS atomics) -------
__global__ __launch_bounds__(256) void k_convT(const float* __restrict__ adj,
    u8* __restrict__ abf, u8* __restrict__ atbf,
    float* __restrict__ degr, float* __restrict__ degc)
{
  __shared__ u8 tN[64][80];
  __shared__ u8 tT[64][80];
  __shared__ float rsum[64];
  __shared__ float cpart[16][64];
  const int tid = threadIdx.x;
  const int bx = blockIdx.x, by = blockIdx.y;
  const int c4 = (tid & 15) * 4;
  const int g  = tid >> 4;
  const int gk = bx*64 + c4;
  float ca0=0.f, ca1=0.f, ca2=0.f, ca3=0.f;
  #pragma unroll
  for (int p=0;p<4;p++){
    int r = p*16 + g;
    int gm = by*64 + r;
    float v0=0.f,v1=0.f,v2=0.f,v3=0.f;
    if (gm < N_NODES && gk + 3 < N_NODES){
      const float4 v = *(const float4*)(adj + (size_t)gm*N_NODES + gk);
      v0=v.x; v1=v.y; v2=v.z; v3=v.w;
    }
    u8 p0=f2e4(v0), p1=f2e4(v1), p2=f2e4(v2), p3=f2e4(v3);
    *(u32*)&tN[r][c4] = (u32)p0 | ((u32)p1<<8) | ((u32)p2<<16) | ((u32)p3<<24);
    tT[c4+0][r]=p0; tT[c4+1][r]=p1; tT[c4+2][r]=p2; tT[c4+3][r]=p3;
    float ls = v0+v1+v2+v3;
    ls += __shfl_xor(ls,1); ls += __shfl_xor(ls,2);
    ls += __shfl_xor(ls,4); ls += __shfl_xor(ls,8);
    if ((tid & 15) == 0) rsum[r] = ls;
    ca0+=v0; ca1+=v1; ca2+=v2; ca3+=v3;
  }
  cpart[g][c4+0]=ca0; cpart[g][c4+1]=ca1; cpart[g][c4+2]=ca2; cpart[g][c4+3]=ca3;
  __syncthreads();
  if (tid < 64){
    int gm = by*64 + tid;
    if (gm < N_NODES && rsum[tid] != 0.f) atomicAdd(&degr[gm], rsum[tid]);
    float cs = 0.f;
    #pragma unroll
    for (int gg=0;gg<16;gg++) cs += cpart[gg][tid];
    int gc = bx*64 + tid;
    if (gc < N_NODES && cs != 0.f) atomicAdd(&degc[gc], cs);
  }
  const int j = tid >> 2, c16 = (tid & 3) * 16;
  *(i32x4*)(abf  + (size_t)(by*64+j)*NP + bx*64 + c16) = *(const i32x4*)(&tN[j][c16]);
  *(i32x4*)(atbf + (size_t)(bx*64+j)*NP + by*64 + c16) = *(const i32x4*)(&tT[j][c16]);
}

// ---------------- x -> fp8 [128][5120] padded ----------------
__global__ void k_xbf(const float* __restrict__ x, u8* __restrict__ xbf){
  int i4 = (blockIdx.x*256 + threadIdx.x)*4;
  int j = i4 / NP, n = i4 - j*NP;
  u32 w = 0;
  if (j < BTOT){
    #pragma unroll
    for (int e=0;e<4;e++){
      float v = (n+e < N_NODES) ? x[(size_t)j*N_NODES + n + e] : 0.f;
      w |= ((u32)f2e4(v)) << (8*e);
    }
  }
  *(u32*)(xbf + i4) = w;
}

// ======= shared fp8 MFMA tile machinery (R4-exact geometry) =======
__device__ __forceinline__ i32x8 frag8(const u8* lds, int row, int kb2){
  int g = GPERM(row & 7);
  int ba = row*128 + ((kb2 ^ g)<<4);
  union { i32x8 v; i32x4 h[2]; } f;
  f.h[0] = *(const i32x4*)(lds + ba);
  f.h[1] = *(const i32x4*)(lds + (ba^16));
  return f.v;
}

// ------- ysl[ks][5120][128] = A(fp8) @ xbf(fp8)^T, counted-vmcnt pipeline -------
__global__ __launch_bounds__(256) void k_sgemm8(const u8* __restrict__ abf,
    const u8* __restrict__ atbf, const u8* __restrict__ B,
    float* __restrict__ y1sl, float* __restrict__ y2sl)
{
  __shared__ __align__(16) u8 lA[2][16384];
  __shared__ __align__(16) u8 lB[2][16384];
  const u8* A = blockIdx.z ? atbf : abf;
  float* ysl = blockIdx.z ? y2sl : y1sl;
  const int tid = threadIdx.x, lane = tid & 63, wv = tid >> 6;
  const int wm = (wv >> 1) * 64, wj = (wv & 1) * 64;
  const int m0 = blockIdx.x * 128;
  const int kbase = blockIdx.y * 640;
  f32x4 acc[4][4] = {};
  const int q = tid >> 3;
  const int sc = ((tid & 7) ^ GPERM(q & 7)) << 4;
  const u8* gA = A + (size_t)(m0 + q)*NP + kbase + sc;
  const u8* gB = B + (size_t)q*NP + kbase + sc;

  #define SSTAGE8(k0, bufA, bufB) do { \
    _Pragma("unroll") \
    for (int s=0;s<4;s++){ \
      GLOAD16(gA + (size_t)(s*32)*NP + (k0), (char*)(bufA) + s*4096 + wv*1024); \
      GLOAD16(gB + (size_t)(s*32)*NP + (k0), (char*)(bufB) + s*4096 + wv*1024); \
    } \
  } while(0)

  SSTAGE8(0,   lA[0], lB[0]);
  SSTAGE8(128, lA[1], lB[1]);
  asm volatile("s_waitcnt vmcnt(8)" ::: "memory");
  __builtin_amdgcn_s_barrier();
  CFENCE();
  __builtin_amdgcn_sched_barrier(0);

  for (int t = 0; t < 5; t++) {
    const int cur = t & 1;
    const u8* bA = lA[cur];
    const u8* bB = lB[cur];
    i32x8 af[4], bfv[4];
    const int kb2 = (lane >> 4) * 2;
    #pragma unroll
    for (int i=0;i<4;i++){
      af[i]  = frag8(bA, wm + i*16 + (lane&15), kb2);
      bfv[i] = frag8(bB, wj + i*16 + (lane&15), kb2);
    }
    __builtin_amdgcn_s_setprio(1);
    #pragma unroll
    for (int i=0;i<4;i++)
      #pragma unroll
      for (int j=0;j<4;j++)
        acc[i][j] = __builtin_amdgcn_mfma_scale_f32_16x16x128_f8f6f4(
            af[i], bfv[j], acc[i][j], 0, 0, 0, 0x7f7f7f7f, 0, 0x7f7f7f7f);
    __builtin_amdgcn_s_setprio(0);
    CFENCE();
    __builtin_amdgcn_s_barrier();
    CFENCE();
    __builtin_amdgcn_sched_barrier(0);
    if (t + 2 < 5) {
      SSTAGE8((t+2)*128, lA[cur], lB[cur]);
      asm volatile("s_waitcnt vmcnt(8)" ::: "memory");
    } else {
      asm volatile("s_waitcnt vmcnt(0)" ::: "memory");
    }
    __builtin_amdgcn_s_barrier();
    CFENCE();
    __builtin_amdgcn_sched_barrier(0);
  }
  #undef SSTAGE8

  float* yb = ysl + (size_t)blockIdx.y * NP * 128;
  #pragma unroll
  for (int i=0;i<4;i++)
    #pragma unroll
    for (int r=0;r<4;r++){
      int row = m0 + wm + i*16 + (lane>>4)*4 + r;
      #pragma unroll
      for (int j=0;j<4;j++){
        int col = wj + j*16 + (lane&15);
        yb[(size_t)row*128 + col] = acc[i][j][r];
      }
    }
}

// ------- reduce 8 K-slices, fold 1/deg, transpose to y[bt][n] -------
__global__ __launch_bounds__(256) void k_yred(const float* __restrict__ y1sl,
    const float* __restrict__ y2sl, const float* __restrict__ degr,
    const float* __restrict__ degc, float* __restrict__ y1r, float* __restrict__ y2r)
{
  __shared__ float tb[128][66];
  const int n0 = blockIdx.x*64;
  const int bt = threadIdx.x & 127, nh = threadIdx.x >> 7;
  const int nl = threadIdx.x & 63, bh = threadIdx.x >> 6;
  #pragma unroll 4
  for (int k=0;k<32;k++){
    int n = nh*32 + k;
    float s = 0.f;
    #pragma unroll
    for (int sl=0; sl<8; sl++) s += y1sl[((size_t)sl*NP + n0+n)*128 + bt];
    tb[bt][n] = s;
  }
  __syncthreads();
  {
    float dv = degr[n0+nl];
    float iv = (dv > 0.f) ? 1.f/dv : 0.f;
    #pragma unroll 4
    for (int b=0;b<32;b++){
      int btw = bh*32 + b;
      y1r[(size_t)btw*NP + n0 + nl] = iv * tb[btw][nl];
    }
  }
  __syncthreads();
  #pragma unroll 4
  for (int k=0;k<32;k++){
    int n = nh*32 + k;
    float s = 0.f;
    #pragma unroll
    for (int sl=0; sl<8; sl++) s += y2sl[((size_t)sl*NP + n0+n)*128 + bt];
    tb[bt][n] = s;
  }
  __syncthreads();
  {
    float dv = degc[n0+nl];
    float iv = (dv > 0.f) ? 1.f/dv : 0.f;
    #pragma unroll 4
    for (int b=0;b<32;b++){
      int btw = bh*32 + b;
      y2r[(size_t)btw*NP + n0 + nl] = iv * tb[btw][nl];
    }
  }
}

// ------- layer-1: h1t(fp8) [j][n] via LDS transpose + h1n(bf16) [n][j] -------
__global__ __launch_bounds__(256) void k_h1(const float* __restrict__ x,
    const float* __restrict__ y1r, const float* __restrict__ y2r,
    const float* __restrict__ consts, u8* __restrict__ h1t, u16* __restrict__ h1n)
{
  __shared__ u8 trT[64][80];
  const int tid = threadIdx.x;
  const int n = tid & 63, d0 = (tid >> 6) * 16;
  const int n0 = blockIdx.x * 64;
  const int bt = blockIdx.y;
  const int gn = n0 + n;
  const bool valid = gn < N_NODES;
  float xv  = valid ? x[(size_t)bt*N_NODES + gn] : 0.f;
  float y1s = y1r[(size_t)bt*NP + gn];
  float y2s = y2r[(size_t)bt*NP + gn];
  float hv[16];
  #pragma unroll
  for (int e=0;e<16;e++){
    int d = d0 + e;
    float v = 0.f;
    if (valid)
      v = fmaxf(xv*consts[d] + y1s*consts[64+d] + y2s*consts[128+d] + consts[192+d], 0.f);
    hv[e] = v;
    trT[d][n] = f2e4(v);
  }
  u16x8 p0, p1;
  #pragma unroll
  for (int e=0;e<8;e++){ p0[e]=f2b(hv[e]); p1[e]=f2b(hv[8+e]); }
  u16* dst = h1n + (size_t)gn*J_DIM + bt*64 + d0;
  *(u16x8*)dst = p0;
  *(u16x8*)(dst+8) = p1;
  __syncthreads();
  const int d = tid >> 2, c16 = (tid & 3) * 16;
  *(i32x4*)(h1t + (size_t)(bt*64+d)*NP + n0 + c16) = *(const i32x4*)(&trT[d][c16]);
}

// ------- big GEMM (z-merged P/Q), counted-vmcnt double-buffered pipeline -------
__global__ __launch_bounds__(256) void k_gemm8(
    const u8* __restrict__ abf, const u8* __restrict__ atbf,
    const u8* __restrict__ Bt, u16* __restrict__ Pb, u16* __restrict__ Qb,
    const float* __restrict__ degr, const float* __restrict__ degc)
{
  __shared__ __align__(16) u8 lA[2][16384];
  __shared__ __align__(16) u8 lB[2][16384];
  const u8* A = blockIdx.z ? atbf : abf;
  u16* C = blockIdx.z ? Qb : Pb;
  const float* dg = blockIdx.z ? degc : degr;
  const int tid = threadIdx.x, lane = tid & 63, wv = tid >> 6;
  const int wm = (wv >> 1) * 64, wj = (wv & 1) * 64;
  const int m0 = blockIdx.x * 128;
  const int j0 = blockIdx.y * 128;
  f32x4 acc[4][4] = {};
  const int q = tid >> 3;
  const int sc = ((tid & 7) ^ GPERM(q & 7)) << 4;
  const u8* gA = A + (size_t)(m0 + q)*NP + sc;
  const u8* gB = Bt + (size_t)(j0 + q)*NP + sc;

  #define STAGE8(k0, bufA, bufB) do { \
    _Pragma("unroll") \
    for (int s=0;s<4;s++){ \
      GLOAD16(gA + (size_t)(s*32)*NP + (k0), (char*)(bufA) + s*4096 + wv*1024); \
      GLOAD16(gB + (size_t)(s*32)*NP + (k0), (char*)(bufB) + s*4096 + wv*1024); \
    } \
  } while(0)

  STAGE8(0,   lA[0], lB[0]);
  STAGE8(128, lA[1], lB[1]);
  asm volatile("s_waitcnt vmcnt(8)" ::: "memory");
  __builtin_amdgcn_s_barrier();
  CFENCE();
  __builtin_amdgcn_sched_barrier(0);

  const int NT = NP/128;  // 40
  for (int t = 0; t < NT; t++) {
    const int cur = t & 1;
    const u8* bA = lA[cur];
    const u8* bB = lB[cur];
    i32x8 af[4], bfv[4];
    const int kb2 = (lane >> 4) * 2;
    #pragma unroll
    for (int i=0;i<4;i++){
      af[i]  = frag8(bA, wm + i*16 + (lane&15), kb2);
      bfv[i] = frag8(bB, wj + i*16 + (lane&15), kb2);
    }
    __builtin_amdgcn_s_setprio(1);
    #pragma unroll
    for (int i=0;i<4;i++)
      #pragma unroll
      for (int j=0;j<4;j++)
        acc[i][j] = __builtin_amdgcn_mfma_scale_f32_16x16x128_f8f6f4(
            af[i], bfv[j], acc[i][j], 0, 0, 0, 0x7f7f7f7f, 0, 0x7f7f7f7f);
    __builtin_amdgcn_s_setprio(0);
    CFENCE();
    __builtin_amdgcn_s_barrier();
    CFENCE();
    __builtin_amdgcn_sched_barrier(0);
    if (t + 2 < NT) {
      STAGE8((t+2)*128, lA[cur], lB[cur]);
      asm volatile("s_waitcnt vmcnt(8)" ::: "memory");
    } else {
      asm volatile("s_waitcnt vmcnt(0)" ::: "memory");
    }
    __builtin_amdgcn_s_barrier();
    CFENCE();
    __builtin_amdgcn_sched_barrier(0);
  }
  #undef STAGE8

  #pragma unroll
  for (int i=0;i<4;i++)
    #pragma unroll
    for (int r=0;r<4;r++){
      int row = m0 + wm + i*16 + (lane>>4)*4 + r;
      float dv = dg[row];
      float scl = (dv > 0.f) ? 1.f/dv : 0.f;
      #pragma unroll
      for (int j=0;j<4;j++){
        int col = j0 + wj + j*16 + (lane&15);
        C[(size_t)row*J_DIM + col] = f2b(acc[i][j][r] * scl);
      }
    }
}

// ------- fused layer-2 + head + row-normalize (hori stores NORMALIZED rows) -------
__global__ __launch_bounds__(256) void k_comb(const u16* __restrict__ h1n,
  const u16* __restrict__ P, const u16* __restrict__ Q,
  const u16* __restrict__ w2t, const float* __restrict__ b2,
  const float* __restrict__ Wf1, const float* __restrict__ bf1,
  const float* __restrict__ Wf2, const float* __restrict__ bf2,
  u16* __restrict__ horin, float* __restrict__ yout)
{
  __shared__ float w1L[64*33];
  __shared__ float hT[64][65];
  __shared__ float b1L[32], w2Ls[32];
  const int tid = threadIdx.x;
  for (int i = tid; i < 2048; i += 256) w1L[(i>>5)*33 + (i&31)] = Wf1[i];
  if (tid < 32){ b1L[tid] = bf1[tid]; w2Ls[tid] = Wf2[tid]; }
  const int lane = tid & 63;
  const int wv = tid >> 6;
  const int n0 = blockIdx.x * 64 + wv * 16;
  const int bt = blockIdx.y;
  const int rl = lane & 15, kh = lane >> 4;

  f32x4 acc[4] = {};
  const size_t rowoff = (size_t)(n0 + rl) * J_DIM + bt*64;
  const u16* bases[3] = { h1n + rowoff, P + rowoff, Q + rowoff };
  #pragma unroll
  for (int s=0;s<3;s++){
    const u16* base = bases[s];
    #pragma unroll
    for (int kk=0;kk<2;kk++){
      short8 af = *(const short8*)(base + kk*32 + kh*8);
      #pragma unroll
      for (int j=0;j<4;j++){
        short8 bf = *(const short8*)(w2t + (j*16+rl)*192 + s*64 + kk*32 + kh*8);
        acc[j] = __builtin_amdgcn_mfma_f32_16x16x32_bf16(af, bf, acc[j], 0,0,0);
      }
    }
  }
  float hvv[4][4];
  #pragma unroll
  for (int j=0;j<4;j++){
    float bias = b2[j*16 + rl];
    #pragma unroll
    for (int r=0;r<4;r++) hvv[j][r] = acc[j][r] + bias;
  }
  float inv[4];
  #pragma unroll
  for (int r=0;r<4;r++){
    float s = hvv[0][r]*hvv[0][r] + hvv[1][r]*hvv[1][r]
            + hvv[2][r]*hvv[2][r] + hvv[3][r]*hvv[3][r];
    s += __shfl_xor(s,1); s += __shfl_xor(s,2);
    s += __shfl_xor(s,4); s += __shfl_xor(s,8);
    inv[r] = 1.f / fmaxf(sqrtf(s), 1e-8f);
  }
  #pragma unroll
  for (int j=0;j<4;j++){
    int d = j*16 + rl;
    #pragma unroll
    for (int r=0;r<4;r++){
      int nn = n0 + kh*4 + r;
      hT[wv*16 + kh*4 + r][d] = hvv[j][r];
      if (nn < N_NODES)
        horin[((size_t)bt*N_NODES + nn)*64 + d] = f2b(hvv[j][r] * inv[r]);
    }
  }
  __syncthreads();
  const int qd = tid & 3, node = tid >> 2;
  float h[16];
  #pragma unroll
  for (int e=0;e<16;e++) h[e] = hT[node][qd*16 + e];
  float yacc = 0.f;
  #pragma unroll
  for (int jj=0; jj<32; jj++){
    float s = 0.f;
    #pragma unroll
    for (int dl=0; dl<16; dl++) s += h[dl]*w1L[(qd*16+dl)*33 + jj];
    s += __shfl_xor(s, 1);
    s += __shfl_xor(s, 2);
    s += b1L[jj];
    yacc += fmaxf(s, 0.f)*w2Ls[jj];
  }
  int gn = blockIdx.x*64 + node;
  if (qd == 0 && gn < N_NODES)
    yout[(size_t)bt*N_NODES + gn] = yacc + bf2[0];
}

// ---------------- InfoNCE loss (pre-normalized rows, unrolled ILP) ----------------
__global__ __launch_bounds__(256) void k_loss(const u16* __restrict__ horin,
  const int* __restrict__ missing, const int* __restrict__ posi, const int* __restrict__ negi,
  const float* __restrict__ degr, const float* __restrict__ degc,
  const float* __restrict__ consts, float* __restrict__ out)
{
  const int lane = threadIdx.x & 63;
  const int wv = threadIdx.x >> 6;
  const int wg = blockIdx.x*4 + wv;   // 0..24575
  const int m = wg & 255;
  const int bt = wg >> 8;
  const bool early = (bt % TT) < 4;

  int na = missing[m];
  float va = b2f(horin[((size_t)bt*N_NODES + na)*64 + lane]);

  float lk[KNEG+1];
  #pragma unroll
  for (int k=0;k<=KNEG;k++){
    int node = (k==0) ? posi[m] : negi[m*KNEG + (k-1)];
    float v;
    if (!early) v = b2f(horin[((size_t)bt*N_NODES + node)*64 + lane]);
    else {
      int vi = (degr[node] > 0.f ? 1 : 0) + (degc[node] > 0.f ? 2 : 0);
      v = consts[448 + vi*64 + lane];
    }
    float dp = va*v;
    #pragma unroll
    for (int o=32;o;o>>=1) dp += __shfl_xor(dp, o);
    lk[k] = dp * 2.f;   // /TEMP, TEMP=0.5
  }
  float mx = lk[0];
  #pragma unroll
  for (int k=1;k<=KNEG;k++) mx = fmaxf(mx, lk[k]);
  float se = 0.f;
  #pragma unroll
  for (int k=0;k<=KNEG;k++) se += expf(lk[k]-mx);
  float term = logf(se) + mx - lk[0];
  __shared__ float red[4];
  if (lane == 0) red[wv] = term;
  __syncthreads();
  if (threadIdx.x == 0)
    atomicAdd(out + 480000, (red[0]+red[1]+red[2]+red[3]) * (1.f/24576.f));
}

extern "C" void kernel_launch(void* const* d_in, const int* in_sizes, int n_in,
                              void* d_out, int out_size, void* d_ws, size_t ws_size,
                              hipStream_t stream)
{
  const float* x   = (const float*)d_in[0];
  const float* adj = (const float*)d_in[1];
  const float* Ws  = (const float*)d_in[2];
  const float* bs  = (const float*)d_in[3];
  const float* W1  = (const float*)d_in[4];
  const float* b1  = (const float*)d_in[5];
  const float* W2  = (const float*)d_in[6];
  const float* b2  = (const float*)d_in[7];
  const float* Wf1 = (const float*)d_in[8];
  const float* bf1 = (const float*)d_in[9];
  const float* Wf2 = (const float*)d_in[10];
  const float* bf2 = (const float*)d_in[11];
  const int* missing = (const int*)d_in[12];
  const int* posi    = (const int*)d_in[13];
  const int* negi    = (const int*)d_in[14];
  float* out = (float*)d_out;

  char* w = (char*)d_ws;
  u8*  abf   = (u8*) (w + 0);             // 26,214,400
  u8*  atbf  = (u8*) (w + 26214400);      // 26,214,400
  u8*  h1t   = (u8*) (w + 52428800);      // 31,457,280
  u16* h1n   = (u16*)(w + 83886080);      // 62,914,560 (bf16 self term)
  u16* Pb    = (u16*)(w + 146800640);     // 62,914,560
  u16* Qb    = (u16*)(w + 209715200);     // 62,914,560
  u8*  xbf   = (u8*) (w + 272629760);     // 655,360
  float* degr = (float*)(w + 273285120);  // 20480
  float* degc = (float*)(w + 273305600);  // 20480
  float* consts = (float*)(w + 273326080);// 4096 (704 floats)
  u16* w2t   = (u16*)(w + 273330176);     // 24576
  // aliases (temporally disjoint):
  u16*   horin = (u16*)(w + 0);           // 61,440,000 over abf/atbf/h1t (dead post-gemms)
  float* y1sl  = (float*)(w + 146800640); // 8 x NP x 128 f32 = 20,971,520 (in Pb)
  float* y2sl  = (float*)(w + 167772160); // 20,971,520 (in Pb)
  float* y1r   = (float*)(w + 209715200); // 128 x NP f32 = 2,621,440 (in Qb, dead pre-gemm-Q)
  float* y2r   = (float*)(w + 212336640); // 2,621,440

  hipMemsetAsync(degr, 0, 40960, stream);         // degr+degc (contiguous)
  hipMemsetAsync(out + 480000, 0, 4, stream);     // loss accumulator

  k_prep<<<1, 64, 0, stream>>>(Ws, bs, W1, b1, W2, b2, consts, w2t);
  k_convT<<<dim3(80,80), 256, 0, stream>>>(adj, abf, atbf, degr, degc);
  k_xbf<<<640, 256, 0, stream>>>(x, xbf);
  k_sgemm8<<<dim3(40,8,2), 256, 0, stream>>>(abf, atbf, xbf, y1sl, y2sl);
  k_yred<<<80, 256, 0, stream>>>(y1sl, y2sl, degr, degc, y1r, y2r);
  k_h1<<<dim3(80,96), 256, 0, stream>>>(x, y1r, y2r, consts, h1t, h1n);
  k_gemm8<<<dim3(40,48,2), 256, 0, stream>>>(abf, atbf, h1t, Pb, Qb, degr, degc);
  k_comb<<<dim3(80,96), 256, 0, stream>>>(h1n, Pb, Qb, w2t, b2, Wf1, bf1, Wf2, bf2, horin, out);
  k_loss<<<6144, 256, 0, stream>>>(horin, missing, posi, negi, degr, degc, consts, out);
}